// Round 4
// baseline (399.376 us; speedup 1.0000x reference)
//
#include <hip/hip_runtime.h>

#define IMG_H 2048
#define IMG_W 2048
#define IMG_C 8

typedef float f32x2 __attribute__((ext_vector_type(2)));
typedef float f32x4 __attribute__((ext_vector_type(4)));

// Two lanes per sample: lane `part` handles channels [4*part, 4*part+4).
// Streaming traffic (coords in, out) uses nontemporal hints so the 128-MiB
// image stays resident in the 256-MiB LLC; gather re-reads then hit LLC.
__global__ __launch_bounds__(256) void idx2pixel_kernel(
    const float* __restrict__ coords,
    const float* __restrict__ visible,
    const float* __restrict__ bias,
    float* __restrict__ out,
    int n)
{
    int tid = blockIdx.x * blockDim.x + threadIdx.x;
    int s    = tid >> 1;
    int part = tid & 1;
    if (s >= n) return;

    f32x2 cv = __builtin_nontemporal_load((const f32x2*)(coords + (size_t)s * 2));
    float b0 = bias[0];
    float b1 = bias[1];

    // idx = coords - bias; c = max(idx, 0); low = min(floor(c), H-2); delta = c - low
    float c0 = fmaxf(cv.x - b0, 0.0f);
    float c1 = fmaxf(cv.y - b1, 0.0f);
    float low0 = fminf(floorf(c0), (float)(IMG_H - 2));
    float low1 = fminf(floorf(c1), (float)(IMG_W - 2));
    float d0 = c0 - low0;
    float d1 = c1 - low1;
    int i0 = (int)low0;
    int i1 = (int)low1;

    // Pixel (i0,i1) quad `part`; +8 floats = pixel (i0,i1+1) same quad.
    const float* p_t = visible + ((size_t)i0 * IMG_W + (size_t)i1) * IMG_C + part * 4;
    const float* p_b = p_t + (size_t)IMG_W * IMG_C;

    f32x4 tl = *(const f32x4*)(p_t);       // visible[i0,   i1,   4p:4p+4]
    f32x4 bl = *(const f32x4*)(p_t + 8);   // visible[i0,   i1+1, 4p:4p+4]
    f32x4 tr = *(const f32x4*)(p_b);       // visible[i0+1, i1,   4p:4p+4]
    f32x4 br = *(const f32x4*)(p_b + 8);   // visible[i0+1, i1+1, 4p:4p+4]

    // mid_bottom = br + d0*(bl-br); mid_top = tr + d0*(tl-tr);
    // out = mid_bottom + d1*(mid_top - mid_bottom)   (same order as reference)
    f32x4 o;
    {
        float mb, mt;
        mb = br.x + d0 * (bl.x - br.x); mt = tr.x + d0 * (tl.x - tr.x);
        o.x = mb + d1 * (mt - mb);
        mb = br.y + d0 * (bl.y - br.y); mt = tr.y + d0 * (tl.y - tr.y);
        o.y = mb + d1 * (mt - mb);
        mb = br.z + d0 * (bl.z - br.z); mt = tr.z + d0 * (tl.z - tr.z);
        o.z = mb + d1 * (mt - mb);
        mb = br.w + d0 * (bl.w - br.w); mt = tr.w + d0 * (tl.w - tr.w);
        o.w = mb + d1 * (mt - mb);
    }

    f32x4* outp = (f32x4*)(out + (size_t)s * IMG_C + part * 4);
    __builtin_nontemporal_store(o, outp);
}

extern "C" void kernel_launch(void* const* d_in, const int* in_sizes, int n_in,
                              void* d_out, int out_size, void* d_ws, size_t ws_size,
                              hipStream_t stream) {
    const float* coords  = (const float*)d_in[0];     // (N, 2) f32
    const float* visible = (const float*)d_in[1];     // (H, W, C) f32
    const float* bias    = (const float*)d_in[2];     // (2,) f32
    float* out = (float*)d_out;                       // (N, C) f32

    int n = in_sizes[0] / 2;          // N samples
    long long threads = 2LL * n;      // 2 lanes per sample
    int block = 256;
    long long grid = (threads + block - 1) / block;
    idx2pixel_kernel<<<(int)grid, block, 0, stream>>>(coords, visible, bias, out, n);
}